// Round 9
// baseline (614.428 us; speedup 1.0000x reference)
//
#include <hip/hip_runtime.h>

// ILCBaseNode: T=32 steps of IF-neuron + grouped-conv feedback.
// One wave (64 lanes) per (batch, group) chain; lane o = output neuron o.
// 32768 chains = 8192 blocks x 4 waves.
//
// R9: ENTIRE kernel body in ONE asm volatile block, literal registers.
//     Five rounds of evidence: regalloc AGPR-homes w[64] and inserts 128
//     v_accvgpr copies/step around any compiler-managed loop boundary
//     (R7 audit: 273 instr/step = 129 asm + 16 loop + 128 copies). With
//     the whole t-loop inside one asm there is no boundary to copy across.
//     Weights live in literal v[100:163] (clobber-listed: compiler avoids
//     them, register file sized to 164+). Matvec = R7's proven schedule
//     (5 rotating SGPRs s91-s95, readlane->fmac distance 10, strict
//     ascending-d single accumulator -- bit-exact). x prefetched 2 iters
//     ahead, s_waitcnt vmcnt(1) (spike store stays in flight). Steps
//     t=30,31 peeled: no OOB loads. ~145 instr/step vs measured 273.
//     Ruled out (do not revisit): LDS spike broadcast (R1: 377us,
//     LDS-pipe-bound); accumulation reorder incl. pk_fma/MFMA (spike
//     threshold flips); ballot+SALU bit-expand (scalar unit shared per CU
//     -> SALU-bound at ~218us).

#define T_STEPS 32
#define BATCH 512
#define OUTD 4096           // 64 groups * 64 neurons
#define STEP_STRIDE ((size_t)BATCH * OUTD)

// ---- asm text helpers --------------------------------------------------
// Matvec register map: v94 = spike (sf), v95 = acc, v100+d = w[d],
// s91-s95 = rotating broadcast scalars.
#define RL(sr, d)  "v_readlane_b32 " #sr ", v94, " #d "\n\t"
#define FM(sr, wv) "v_fmac_f32 v95, " #sr ", " #wv "\n\t"
#define PAIR(sr, wv, d) FM(sr, wv) RL(sr, d)

// 64 readlane + 64 fmac; every s-reg write has 10 instruction slots before
// its consuming fmac; fmac order strictly ascending d (bit-exact).
#define MATVEC64 \
  RL(s91,0) RL(s92,1) RL(s93,2) RL(s94,3) RL(s95,4) \
  PAIR(s91,v100,5)  PAIR(s92,v101,6)  PAIR(s93,v102,7)  PAIR(s94,v103,8)  PAIR(s95,v104,9)  \
  PAIR(s91,v105,10) PAIR(s92,v106,11) PAIR(s93,v107,12) PAIR(s94,v108,13) PAIR(s95,v109,14) \
  PAIR(s91,v110,15) PAIR(s92,v111,16) PAIR(s93,v112,17) PAIR(s94,v113,18) PAIR(s95,v114,19) \
  PAIR(s91,v115,20) PAIR(s92,v116,21) PAIR(s93,v117,22) PAIR(s94,v118,23) PAIR(s95,v119,24) \
  PAIR(s91,v120,25) PAIR(s92,v121,26) PAIR(s93,v122,27) PAIR(s94,v123,28) PAIR(s95,v124,29) \
  PAIR(s91,v125,30) PAIR(s92,v126,31) PAIR(s93,v127,32) PAIR(s94,v128,33) PAIR(s95,v129,34) \
  PAIR(s91,v130,35) PAIR(s92,v131,36) PAIR(s93,v132,37) PAIR(s94,v133,38) PAIR(s95,v134,39) \
  PAIR(s91,v135,40) PAIR(s92,v136,41) PAIR(s93,v137,42) PAIR(s94,v138,43) PAIR(s95,v139,44) \
  PAIR(s91,v140,45) PAIR(s92,v141,46) PAIR(s93,v142,47) PAIR(s94,v143,48) PAIR(s95,v144,49) \
  PAIR(s91,v145,50) PAIR(s92,v146,51) PAIR(s93,v147,52) PAIR(s94,v148,53) PAIR(s95,v149,54) \
  PAIR(s91,v150,55) PAIR(s92,v151,56) PAIR(s93,v152,57) PAIR(s94,v153,58) PAIR(s95,v154,59) \
  PAIR(s91,v155,60) PAIR(s92,v156,61) PAIR(s93,v157,62) PAIR(s94,v158,63) \
  FM(s95,v159) FM(s91,v160) FM(s92,v161) FM(s93,v162) FM(s94,v163)

// Charge/fire/reset/store. v98=xt, v97=fb, v96=v, v92=1.0f, v91=0.0f.
// (v-1.0>=0) == (v>=1.0) exactly in fp32 (Sterbenz), matching R0.
// Gap cndmask(v94) -> first readlane: 4 instrs + s_nop 1 (lane-crossing
// source hazard margin, per R7).
#define CHARGE \
  "v_add_f32 v93, v98, v97\n\t"           /* x = xt + fb            */ \
  "v_add_f32 v96, v96, v93\n\t"           /* v = v + x              */ \
  "v_cmp_le_f32 vcc, 1.0, v96\n\t"        /* sp = v >= 1.0          */ \
  "v_cndmask_b32 v94, 0, v92, vcc\n\t"    /* sf = sp ? 1.0 : 0.0    */ \
  "v_cndmask_b32 v96, v96, v91, vcc\n\t"  /* v  = sp ? 0.0 : v      */ \
  "global_store_dword v77, v94, %5\n\t"   /* emit spike             */ \
  "v_add_u32 v77, 0x800000, v77\n\t"      /* out off += 8 MiB       */ \
  "v_mov_b32 v95, 0\n\t"                  /* acc = 0                */ \
  "s_nop 1\n\t"

#define FBBIAS "v_add_f32 v97, %3, v95\n\t"  /* fb = acc + bias (comm.) */

// Wait for the 2-iters-ago-issued x load (1 store may stay in flight),
// rotate buffers, issue load for t+2.
#define NEXTX \
  "s_waitcnt vmcnt(1)\n\t" \
  "v_mov_b32 v98, v99\n\t" \
  "v_add_u32 v76, 0x800000, v76\n\t" \
  "global_load_dword v99, v76, %4\n\t"

__global__ __launch_bounds__(256)
void ilc_snn_kernel(const float* __restrict__ x_seq,
                    const float* __restrict__ conn_w,
                    const float* __restrict__ conn_b,
                    float* __restrict__ out)
{
    const int lane  = threadIdx.x & 63;
    const int wid   = threadIdx.x >> 6;
    const int chain = blockIdx.x * 4 + wid;   // 0..32767
    const int b     = chain >> 6;             // 0..511
    const int a     = chain & 63;             // 0..63

    const unsigned base  = (unsigned)(b * OUTD + a * 64 + lane);
    const unsigned xoff  = base * 4u;                       // byte offsets (u32: max ~260MB)
    const unsigned ooff  = base * 4u;
    const unsigned woff  = (unsigned)(a * 64 + lane) * 256u;
    const float    bias  = conn_b[a * 64 + lane];

    asm volatile(
        // ---- init ----
        "v_mov_b32 v76, %0\n\t"            // x byte-offset cursor
        "v_mov_b32 v77, %1\n\t"            // out byte-offset cursor
        "v_mov_b32 v91, 0\n\t"             // 0.0f
        "v_mov_b32 v92, 1.0\n\t"           // 1.0f
        "v_mov_b32 v96, 0\n\t"             // v  = 0
        "v_mov_b32 v97, 0\n\t"             // fb = 0
        // ---- weights: w[0:63] -> v[100:163] ----
        "global_load_dwordx4 v[100:103], %2, %6 offset:0\n\t"
        "global_load_dwordx4 v[104:107], %2, %6 offset:16\n\t"
        "global_load_dwordx4 v[108:111], %2, %6 offset:32\n\t"
        "global_load_dwordx4 v[112:115], %2, %6 offset:48\n\t"
        "global_load_dwordx4 v[116:119], %2, %6 offset:64\n\t"
        "global_load_dwordx4 v[120:123], %2, %6 offset:80\n\t"
        "global_load_dwordx4 v[124:127], %2, %6 offset:96\n\t"
        "global_load_dwordx4 v[128:131], %2, %6 offset:112\n\t"
        "global_load_dwordx4 v[132:135], %2, %6 offset:128\n\t"
        "global_load_dwordx4 v[136:139], %2, %6 offset:144\n\t"
        "global_load_dwordx4 v[140:143], %2, %6 offset:160\n\t"
        "global_load_dwordx4 v[144:147], %2, %6 offset:176\n\t"
        "global_load_dwordx4 v[148:151], %2, %6 offset:192\n\t"
        "global_load_dwordx4 v[152:155], %2, %6 offset:208\n\t"
        "global_load_dwordx4 v[156:159], %2, %6 offset:224\n\t"
        "global_load_dwordx4 v[160:163], %2, %6 offset:240\n\t"
        // ---- x0, then x1 in flight ----
        "global_load_dword v98, v76, %4\n\t"
        "s_waitcnt vmcnt(0)\n\t"
        "v_add_u32 v76, 0x800000, v76\n\t"
        "global_load_dword v99, v76, %4\n\t"
        // ---- main loop t = 0..29 ----
        "s_mov_b32 s90, 30\n\t"
        "Lmain_%=:\n\t"
        CHARGE
        MATVEC64
        FBBIAS
        NEXTX
        "s_sub_u32 s90, s90, 1\n\t"
        "s_cmp_lg_u32 s90, 0\n\t"
        "s_cbranch_scc1 Lmain_%=\n\t"
        // ---- t = 30 (no further prefetch) ----
        CHARGE
        MATVEC64
        FBBIAS
        "s_waitcnt vmcnt(1)\n\t"
        "v_mov_b32 v98, v99\n\t"
        // ---- t = 31 (spike only; fb unused) ----
        CHARGE
        : /* no outputs */
        : "v"(xoff), "v"(ooff), "v"(woff), "v"(bias),
          "s"(x_seq), "s"(out), "s"(conn_w)
        : "memory", "vcc", "scc",
          "s90","s91","s92","s93","s94","s95",
          "v76","v77","v91","v92","v93","v94","v95","v96","v97","v98","v99",
          "v100","v101","v102","v103","v104","v105","v106","v107",
          "v108","v109","v110","v111","v112","v113","v114","v115",
          "v116","v117","v118","v119","v120","v121","v122","v123",
          "v124","v125","v126","v127","v128","v129","v130","v131",
          "v132","v133","v134","v135","v136","v137","v138","v139",
          "v140","v141","v142","v143","v144","v145","v146","v147",
          "v148","v149","v150","v151","v152","v153","v154","v155",
          "v156","v157","v158","v159","v160","v161","v162","v163");
}

extern "C" void kernel_launch(void* const* d_in, const int* in_sizes, int n_in,
                              void* d_out, int out_size, void* d_ws, size_t ws_size,
                              hipStream_t stream) {
    const float* x_seq  = (const float*)d_in[0];
    const float* conn_w = (const float*)d_in[1];
    const float* conn_b = (const float*)d_in[2];
    float* out = (float*)d_out;

    dim3 grid(8192);   // 32768 chains / 4 waves per block
    dim3 block(256);
    hipLaunchKernelGGL(ilc_snn_kernel, grid, block, 0, stream,
                       x_seq, conn_w, conn_b, out);
}